// Round 1
// baseline (1731.456 us; speedup 1.0000x reference)
//
#include <hip/hip_runtime.h>
#include <hip/hip_bf16.h>
#include <math.h>

// Problem: B=2, H=16, T=2048, D=64. fp32 in/out.
// out  = attn @ v          : (B,H,T,D)  = 4,194,304 floats
// attn = softmax(qr krT/8) : (B,H,T,T)  = 134,217,728 floats
// d_out = [out | attn] concatenated.

#define T_SEQ  2048
#define D_HEAD 64
#define BH_N   32
#define CHUNKS 32            // T / 64
#define ROWS_PER_BLOCK 16
#define ROWS_PER_WAVE  4
#define OUT_ELEMS (BH_N * T_SEQ * D_HEAD)   // 4,194,304

// cos/sin tables: [T][32] each (freq index j = d % 32)
__global__ void rope_table_kernel(float* __restrict__ ctab, float* __restrict__ stab) {
    int i = blockIdx.x * blockDim.x + threadIdx.x;
    if (i >= T_SEQ * 32) return;
    int t = i >> 5;
    int j = i & 31;
    float invf = powf(10000.0f, -(float)j / 32.0f);
    float a = (float)t * invf;
    ctab[i] = cosf(a);
    stab[i] = sinf(a);
}

__device__ __forceinline__ float4 rope4(float4 a, float4 b, float4 c, float4 s, bool lo) {
    float4 r;
    if (lo) {            // d < 32 : x1*c - x2*s
        r.x = a.x * c.x - b.x * s.x;
        r.y = a.y * c.y - b.y * s.y;
        r.z = a.z * c.z - b.z * s.z;
        r.w = a.w * c.w - b.w * s.w;
    } else {             // d >= 32 : x2*c + x1*s  (a = x[d], b = x[d-32])
        r.x = a.x * c.x + b.x * s.x;
        r.y = a.y * c.y + b.y * s.y;
        r.z = a.z * c.z + b.z * s.z;
        r.w = a.w * c.w + b.w * s.w;
    }
    return r;
}

__global__ __launch_bounds__(256, 2)
void attn_kernel(const float* __restrict__ q, const float* __restrict__ k,
                 const float* __restrict__ v, const float* __restrict__ ctab,
                 const float* __restrict__ stab, float* __restrict__ out,
                 float* __restrict__ attn)
{
    // K/V chunk tile: 64 rows, stride 68 floats (keeps ds_read_b128 at bank floor)
    __shared__ float tile[64 * 68];
    __shared__ float qs[16 * 68];
    __shared__ float ps[16 * 64];

    const int bh  = blockIdx.y;
    const int t0  = blockIdx.x * ROWS_PER_BLOCK;
    const int tid = threadIdx.x;
    const int lane = tid & 63;
    const int w    = tid >> 6;

    const float* qg = q + (size_t)bh * T_SEQ * D_HEAD;
    const float* kg = k + (size_t)bh * T_SEQ * D_HEAD;
    const float* vg = v + (size_t)bh * T_SEQ * D_HEAD;
    float* outg  = out  + (size_t)bh * T_SEQ * D_HEAD;
    float* attng = attn + (size_t)bh * T_SEQ * T_SEQ;

    // ---- stage Q rows: rope + pre-scale by 1/sqrt(D)=1/8 ----
    {
        const int row = tid >> 4;      // 0..15
        const int c4  = tid & 15;      // float4 column
        const int trow = t0 + row;
        const float4* qr4 = (const float4*)(qg + (size_t)trow * D_HEAD);
        float4 a = qr4[c4];
        float4 b = qr4[c4 ^ 8];
        float4 c = ((const float4*)(ctab + trow * 32))[c4 & 7];
        float4 s = ((const float4*)(stab + trow * 32))[c4 & 7];
        float4 r = rope4(a, b, c, s, c4 < 8);
        r.x *= 0.125f; r.y *= 0.125f; r.z *= 0.125f; r.w *= 0.125f;
        *(float4*)&qs[row * 68 + c4 * 4] = r;
    }
    __syncthreads();

    float sc[ROWS_PER_WAVE][CHUNKS];   // per-lane scores: s = ch*64 + lane
    #pragma unroll
    for (int r = 0; r < ROWS_PER_WAVE; ++r)
        #pragma unroll
        for (int cc = 0; cc < CHUNKS; ++cc) sc[r][cc] = 0.0f;

    // ---- phase 1: scores (QK^T with rope'd K) ----
    #pragma unroll
    for (int ch = 0; ch < CHUNKS; ++ch) {
        const int c4 = tid & 15;
        const int r0 = tid >> 4;
        #pragma unroll
        for (int i = 0; i < 4; ++i) {
            const int srow = r0 + i * 16;           // 0..63
            const int sg   = ch * 64 + srow;
            const float4* kr4 = (const float4*)(kg + (size_t)sg * D_HEAD);
            float4 a = kr4[c4];
            float4 b = kr4[c4 ^ 8];
            float4 c = ((const float4*)(ctab + sg * 32))[c4 & 7];
            float4 s = ((const float4*)(stab + sg * 32))[c4 & 7];
            float4 r = rope4(a, b, c, s, c4 < 8);
            *(float4*)&tile[srow * 68 + c4 * 4] = r;
        }
        __syncthreads();
        #pragma unroll
        for (int c16 = 0; c16 < 16; ++c16) {
            float4 kk = *(const float4*)&tile[lane * 68 + c16 * 4];
            #pragma unroll
            for (int r = 0; r < ROWS_PER_WAVE; ++r) {
                float4 qq = *(const float4*)&qs[(w * ROWS_PER_WAVE + r) * 68 + c16 * 4];
                sc[r][ch] += qq.x * kk.x + qq.y * kk.y + qq.z * kk.z + qq.w * kk.w;
            }
        }
        __syncthreads();
    }

    // ---- softmax over full row (scores already scaled via q) ----
    #pragma unroll
    for (int r = 0; r < ROWS_PER_WAVE; ++r) {
        float m = sc[r][0];
        #pragma unroll
        for (int cc = 1; cc < CHUNKS; ++cc) m = fmaxf(m, sc[r][cc]);
        #pragma unroll
        for (int off = 32; off > 0; off >>= 1) m = fmaxf(m, __shfl_xor(m, off, 64));
        float l = 0.0f;
        #pragma unroll
        for (int cc = 0; cc < CHUNKS; ++cc) {
            float e = __expf(sc[r][cc] - m);
            sc[r][cc] = e;
            l += e;
        }
        #pragma unroll
        for (int off = 32; off > 0; off >>= 1) l += __shfl_xor(l, off, 64);
        float inv_l = 1.0f / l;
        #pragma unroll
        for (int cc = 0; cc < CHUNKS; ++cc) sc[r][cc] *= inv_l;
    }

    // ---- phase 2: attn writeback + PV ----
    float acc[ROWS_PER_WAVE] = {0.0f, 0.0f, 0.0f, 0.0f};
    #pragma unroll
    for (int ch = 0; ch < CHUNKS; ++ch) {
        const int c4 = tid & 15;
        const int r0 = tid >> 4;
        #pragma unroll
        for (int i = 0; i < 4; ++i) {
            const int srow = r0 + i * 16;
            const int sg   = ch * 64 + srow;
            float4 a = ((const float4*)(vg + (size_t)sg * D_HEAD))[c4];
            *(float4*)&tile[srow * 68 + c4 * 4] = a;
        }
        #pragma unroll
        for (int r = 0; r < ROWS_PER_WAVE; ++r) {
            float pv = sc[r][ch];
            ps[(w * ROWS_PER_WAVE + r) * 64 + lane] = pv;
            attng[(size_t)(t0 + w * ROWS_PER_WAVE + r) * T_SEQ + ch * 64 + lane] = pv;
        }
        __syncthreads();
        #pragma unroll
        for (int s4 = 0; s4 < 16; ++s4) {
            float4 p4[ROWS_PER_WAVE];
            #pragma unroll
            for (int r = 0; r < ROWS_PER_WAVE; ++r)
                p4[r] = *(const float4*)&ps[(w * ROWS_PER_WAVE + r) * 64 + s4 * 4];
            float vv0 = tile[(s4 * 4 + 0) * 68 + lane];
            float vv1 = tile[(s4 * 4 + 1) * 68 + lane];
            float vv2 = tile[(s4 * 4 + 2) * 68 + lane];
            float vv3 = tile[(s4 * 4 + 3) * 68 + lane];
            #pragma unroll
            for (int r = 0; r < ROWS_PER_WAVE; ++r)
                acc[r] += p4[r].x * vv0 + p4[r].y * vv1 + p4[r].z * vv2 + p4[r].w * vv3;
        }
        __syncthreads();
    }

    #pragma unroll
    for (int r = 0; r < ROWS_PER_WAVE; ++r)
        outg[(size_t)(t0 + w * ROWS_PER_WAVE + r) * D_HEAD + lane] = acc[r];
}

extern "C" void kernel_launch(void* const* d_in, const int* in_sizes, int n_in,
                              void* d_out, int out_size, void* d_ws, size_t ws_size,
                              hipStream_t stream) {
    const float* q = (const float*)d_in[0];
    const float* k = (const float*)d_in[1];
    const float* v = (const float*)d_in[2];
    float* out  = (float*)d_out;
    float* attn = out + (size_t)OUT_ELEMS;

    float* ctab = (float*)d_ws;               // T*32 floats
    float* stab = ctab + T_SEQ * 32;          // T*32 floats (512 KB total)

    rope_table_kernel<<<dim3((T_SEQ * 32 + 255) / 256), dim3(256), 0, stream>>>(ctab, stab);

    dim3 grid(T_SEQ / ROWS_PER_BLOCK, BH_N);
    attn_kernel<<<grid, dim3(256), 0, stream>>>(q, k, v, ctab, stab, out, attn);
}

// Round 3
// 382.980 us; speedup vs baseline: 4.5210x; 4.5210x over previous
//
#include <hip/hip_runtime.h>
#include <hip/hip_bf16.h>
#include <math.h>

// B=2,H=16 (BH=32), T=2048, D=64. fp32 in/out.
// d_out = [out (BH*T*64) | attn (BH*T*T)] fp32.
//
// Strategy: RoPE'd Q,K and V^T precomputed as bf16 hi/lo pairs in d_ws.
// Attention kernel uses compensated bf16 MFMA (hi*hi + hi*lo + lo*hi) so
// scores are fp32-accurate; softmax without max-subtraction (scores <= ~16,
// exp() safe in fp32); attn written with nontemporal stores; PV via MFMA with
// P split hi/lo through a per-wave LDS round-trip.

#define T_SEQ  2048
#define D_HEAD 64
#define BH_N   32
#define BM     32            // q rows per block
#define WAVES  8
#define WCOLS  256           // score columns per wave
#define OUT_ELEMS (BH_N * T_SEQ * D_HEAD)

typedef __attribute__((ext_vector_type(8))) short bf16x8;
typedef __attribute__((ext_vector_type(4))) float f32x4;

__device__ __forceinline__ unsigned short f2bf(float x) {
    __hip_bfloat16 h = __float2bfloat16(x);
    return *reinterpret_cast<unsigned short*>(&h);
}
__device__ __forceinline__ float bf2f(unsigned short u) {
    __hip_bfloat16 h;
    *reinterpret_cast<unsigned short*>(&h) = u;
    return __bfloat162float(h);
}

// ---------------- precompute: rope tables ----------------
__global__ void rope_table_kernel(float* __restrict__ ctab, float* __restrict__ stab) {
    int i = blockIdx.x * blockDim.x + threadIdx.x;
    if (i >= T_SEQ * 32) return;
    int t = i >> 5;
    int j = i & 31;
    float invf = powf(10000.0f, -(float)j / 32.0f);
    float a = (float)t * invf;
    ctab[i] = cosf(a);
    stab[i] = sinf(a);
}

// ---------------- precompute: rope + hi/lo split for Q,K ----------------
__global__ __launch_bounds__(256)
void ropesplit_kernel(const float* __restrict__ X, const float* __restrict__ ctab,
                      const float* __restrict__ stab, unsigned short* __restrict__ H,
                      unsigned short* __restrict__ L, float scale)
{
    const int r  = blockIdx.x * 16 + (threadIdx.x >> 4);   // global row in [0, BH*T)
    const int c4 = threadIdx.x & 15;
    const int t  = r & (T_SEQ - 1);
    const float4* xr = (const float4*)(X + (size_t)r * 64);
    float4 a = xr[c4];
    float4 b = xr[c4 ^ 8];
    float4 c = ((const float4*)(ctab + t * 32))[c4 & 7];
    float4 s = ((const float4*)(stab + t * 32))[c4 & 7];
    float4 ro;
    if (c4 < 8) {
        ro.x = a.x * c.x - b.x * s.x; ro.y = a.y * c.y - b.y * s.y;
        ro.z = a.z * c.z - b.z * s.z; ro.w = a.w * c.w - b.w * s.w;
    } else {
        ro.x = a.x * c.x + b.x * s.x; ro.y = a.y * c.y + b.y * s.y;
        ro.z = a.z * c.z + b.z * s.z; ro.w = a.w * c.w + b.w * s.w;
    }
    ro.x *= scale; ro.y *= scale; ro.z *= scale; ro.w *= scale;
    ushort4 h, l;
    h.x = f2bf(ro.x); l.x = f2bf(ro.x - bf2f(h.x));
    h.y = f2bf(ro.y); l.y = f2bf(ro.y - bf2f(h.y));
    h.z = f2bf(ro.z); l.z = f2bf(ro.z - bf2f(h.z));
    h.w = f2bf(ro.w); l.w = f2bf(ro.w - bf2f(h.w));
    *(ushort4*)(H + (size_t)r * 64 + c4 * 4) = h;
    *(ushort4*)(L + (size_t)r * 64 + c4 * 4) = l;
}

// ---------------- precompute: V transpose + hi/lo split ----------------
__global__ __launch_bounds__(256)
void vtrans_kernel(const float* __restrict__ V, unsigned short* __restrict__ Vth,
                   unsigned short* __restrict__ Vtl)
{
    __shared__ float tile[64][65];
    const int bh = blockIdx.y;
    const int tt = blockIdx.x;            // 64-row t-tile
    const float* vg = V + ((size_t)bh * T_SEQ + tt * 64) * 64;
    #pragma unroll
    for (int i = 0; i < 4; ++i) {
        const int row = (threadIdx.x >> 4) + i * 16;
        const int c4  = threadIdx.x & 15;
        float4 a = *(const float4*)(vg + (size_t)row * 64 + c4 * 4);
        tile[row][c4 * 4 + 0] = a.x; tile[row][c4 * 4 + 1] = a.y;
        tile[row][c4 * 4 + 2] = a.z; tile[row][c4 * 4 + 3] = a.w;
    }
    __syncthreads();
    #pragma unroll
    for (int i = 0; i < 4; ++i) {
        const int d   = (threadIdx.x >> 4) + i * 16;
        const int tc4 = threadIdx.x & 15;
        ushort4 h, l;
        float x0 = tile[tc4 * 4 + 0][d];
        float x1 = tile[tc4 * 4 + 1][d];
        float x2 = tile[tc4 * 4 + 2][d];
        float x3 = tile[tc4 * 4 + 3][d];
        h.x = f2bf(x0); l.x = f2bf(x0 - bf2f(h.x));
        h.y = f2bf(x1); l.y = f2bf(x1 - bf2f(h.y));
        h.z = f2bf(x2); l.z = f2bf(x2 - bf2f(h.z));
        h.w = f2bf(x3); l.w = f2bf(x3 - bf2f(h.w));
        size_t off = ((size_t)bh * 64 + d) * T_SEQ + tt * 64 + tc4 * 4;
        *(ushort4*)(Vth + off) = h;
        *(ushort4*)(Vtl + off) = l;
    }
}

// ---------------- main attention kernel ----------------
__global__ __launch_bounds__(512, 2)
void attn_mfma_kernel(const unsigned short* __restrict__ Qh, const unsigned short* __restrict__ Ql,
                      const unsigned short* __restrict__ Kh, const unsigned short* __restrict__ Kl,
                      const unsigned short* __restrict__ Vth, const unsigned short* __restrict__ Vtl,
                      float* __restrict__ out, float* __restrict__ attn)
{
    __shared__ float rsum[WAVES][BM];
    __shared__ __align__(16) unsigned short pbuf[WAVES][2][32][88];  // 90112 B; stride 88 keeps b128 reads 16B-aligned & bank-uniform

    const int tid  = threadIdx.x;
    const int lane = tid & 63;
    const int w    = tid >> 6;
    const int lrow = lane & 15;
    const int lgrp = lane >> 4;

    // XCD-aware swizzle: blocks of one bh stay on one XCD's L2 (2048 % 8 == 0, bijective)
    const int lid = blockIdx.x;
    const int vid = (lid & 7) * 256 + (lid >> 3);
    const int bh  = vid >> 6;
    const int m   = vid & 63;
    const int t0  = m * BM;
    const int c0  = w * WCOLS;

    const size_t base = (size_t)bh * T_SEQ * D_HEAD;
    const unsigned short* qh  = Qh  + base + (size_t)t0 * D_HEAD;
    const unsigned short* ql  = Ql  + base + (size_t)t0 * D_HEAD;
    const unsigned short* kh  = Kh  + base;
    const unsigned short* kl  = Kl  + base;
    const unsigned short* vth = Vth + base;   // layout [bh][64][T]
    const unsigned short* vtl = Vtl + base;

    // --- Q fragments (A-operand): row = lane&15, k-slice = (lane>>4)*8 ---
    bf16x8 qfh[2][2], qfl[2][2];
    #pragma unroll
    for (int mt = 0; mt < 2; ++mt)
        #pragma unroll
        for (int ks = 0; ks < 2; ++ks) {
            const int off = (mt * 16 + lrow) * 64 + ks * 32 + lgrp * 8;
            qfh[mt][ks] = *(const bf16x8*)(qh + off);
            qfl[mt][ks] = *(const bf16x8*)(ql + off);
        }

    // --- scores: S = Qh*Kh + Qh*Kl + Ql*Kh (compensated bf16) ---
    f32x4 s[2][16];
    #pragma unroll
    for (int mt = 0; mt < 2; ++mt)
        #pragma unroll
        for (int nt = 0; nt < 16; ++nt)
            s[mt][nt] = (f32x4){0.f, 0.f, 0.f, 0.f};

    #pragma unroll
    for (int nt = 0; nt < 16; ++nt) {
        const int coff = (c0 + nt * 16 + lrow) * 64 + lgrp * 8;
        bf16x8 k_h0 = *(const bf16x8*)(kh + coff);
        bf16x8 k_h1 = *(const bf16x8*)(kh + coff + 32);
        bf16x8 k_l0 = *(const bf16x8*)(kl + coff);
        bf16x8 k_l1 = *(const bf16x8*)(kl + coff + 32);
        #pragma unroll
        for (int mt = 0; mt < 2; ++mt) {
            f32x4 acc = s[mt][nt];
            acc = __builtin_amdgcn_mfma_f32_16x16x32_bf16(qfh[mt][0], k_h0, acc, 0, 0, 0);
            acc = __builtin_amdgcn_mfma_f32_16x16x32_bf16(qfh[mt][1], k_h1, acc, 0, 0, 0);
            acc = __builtin_amdgcn_mfma_f32_16x16x32_bf16(qfh[mt][0], k_l0, acc, 0, 0, 0);
            acc = __builtin_amdgcn_mfma_f32_16x16x32_bf16(qfh[mt][1], k_l1, acc, 0, 0, 0);
            acc = __builtin_amdgcn_mfma_f32_16x16x32_bf16(qfl[mt][0], k_h0, acc, 0, 0, 0);
            acc = __builtin_amdgcn_mfma_f32_16x16x32_bf16(qfl[mt][1], k_h1, acc, 0, 0, 0);
            s[mt][nt] = acc;
        }
    }

    // --- exp (no max subtraction: |score| <= ~16, exp safe in fp32) ---
    #pragma unroll
    for (int mt = 0; mt < 2; ++mt)
        #pragma unroll
        for (int nt = 0; nt < 16; ++nt)
            #pragma unroll
            for (int j = 0; j < 4; ++j)
                s[mt][nt][j] = __expf(s[mt][nt][j]);

    // --- row sums: in-lane over nt, shfl over the 16 lanes of a row-group ---
    float rp[2][4];
    #pragma unroll
    for (int mt = 0; mt < 2; ++mt)
        #pragma unroll
        for (int j = 0; j < 4; ++j) {
            float acc = 0.f;
            #pragma unroll
            for (int nt = 0; nt < 16; ++nt) acc += s[mt][nt][j];
            rp[mt][j] = acc;
        }
    #pragma unroll
    for (int off = 1; off < 16; off <<= 1)
        #pragma unroll
        for (int mt = 0; mt < 2; ++mt)
            #pragma unroll
            for (int j = 0; j < 4; ++j)
                rp[mt][j] += __shfl_xor(rp[mt][j], off, 64);
    if (lrow == 0) {
        #pragma unroll
        for (int mt = 0; mt < 2; ++mt)
            #pragma unroll
            for (int j = 0; j < 4; ++j)
                rsum[w][mt * 16 + lgrp * 4 + j] = rp[mt][j];
    }
    __syncthreads();
    float inv[2][4];
    #pragma unroll
    for (int mt = 0; mt < 2; ++mt)
        #pragma unroll
        for (int j = 0; j < 4; ++j) {
            const int row = mt * 16 + lgrp * 4 + j;
            float tot = 0.f;
            #pragma unroll
            for (int ww = 0; ww < 8; ++ww) tot += rsum[ww][row];
            inv[mt][j] = 1.0f / tot;
        }

    // --- normalize + attn writeback (nontemporal; streaming) ---
    float* arow = attn + (size_t)bh * T_SEQ * T_SEQ + (size_t)(t0 + lgrp * 4) * T_SEQ + c0 + lrow;
    #pragma unroll
    for (int mt = 0; mt < 2; ++mt)
        #pragma unroll
        for (int j = 0; j < 4; ++j) {
            #pragma unroll
            for (int nt = 0; nt < 16; ++nt) s[mt][nt][j] *= inv[mt][j];
            float* rowp = arow + (mt * 16 + j) * T_SEQ;
            #pragma unroll
            for (int nt = 0; nt < 16; ++nt)
                __builtin_nontemporal_store(s[mt][nt][j], rowp + nt * 16);
        }

    // --- PV: out += P * V via MFMA, P split hi/lo through per-wave LDS ---
    f32x4 o[2][4];
    #pragma unroll
    for (int mt = 0; mt < 2; ++mt)
        #pragma unroll
        for (int nd = 0; nd < 4; ++nd)
            o[mt][nd] = (f32x4){0.f, 0.f, 0.f, 0.f};

    unsigned short* pbh = &pbuf[w][0][0][0];
    unsigned short* pbl = &pbuf[w][1][0][0];
    #pragma unroll
    for (int cc = 0; cc < 4; ++cc) {
        // convert this 64-col chunk of P to bf16 hi/lo in LDS (C-layout addresses)
        #pragma unroll
        for (int mt = 0; mt < 2; ++mt)
            #pragma unroll
            for (int n4 = 0; n4 < 4; ++n4) {
                const int nt  = cc * 4 + n4;
                const int row = mt * 16 + lgrp * 4;
                const int col = n4 * 16 + lrow;
                #pragma unroll
                for (int j = 0; j < 4; ++j) {
                    float x = s[mt][nt][j];
                    unsigned short h = f2bf(x);
                    unsigned short l = f2bf(x - bf2f(h));
                    pbh[(row + j) * 88 + col] = h;
                    pbl[(row + j) * 88 + col] = l;
                }
            }
        asm volatile("s_waitcnt lgkmcnt(0)" ::: "memory");
        __builtin_amdgcn_sched_barrier(0);
        #pragma unroll
        for (int ks2 = 0; ks2 < 2; ++ks2) {
            bf16x8 pah[2], pal[2];
            #pragma unroll
            for (int mt = 0; mt < 2; ++mt) {
                const int poff = (mt * 16 + lrow) * 88 + ks2 * 32 + lgrp * 8;
                pah[mt] = *(const bf16x8*)(pbh + poff);
                pal[mt] = *(const bf16x8*)(pbl + poff);
            }
            #pragma unroll
            for (int nd = 0; nd < 4; ++nd) {
                const size_t voff = (size_t)(nd * 16 + lrow) * T_SEQ + c0 + cc * 64 + ks2 * 32 + lgrp * 8;
                bf16x8 vh = *(const bf16x8*)(vth + voff);
                bf16x8 vl = *(const bf16x8*)(vtl + voff);
                #pragma unroll
                for (int mt = 0; mt < 2; ++mt) {
                    f32x4 a = o[mt][nd];
                    a = __builtin_amdgcn_mfma_f32_16x16x32_bf16(pah[mt], vh, a, 0, 0, 0);
                    a = __builtin_amdgcn_mfma_f32_16x16x32_bf16(pah[mt], vl, a, 0, 0, 0);
                    a = __builtin_amdgcn_mfma_f32_16x16x32_bf16(pal[mt], vh, a, 0, 0, 0);
                    o[mt][nd] = a;
                }
            }
        }
    }

    // --- deterministic cross-wave out reduction through LDS (reuse pbuf) ---
    __syncthreads();                       // all waves done reading their pbuf
    float* pout = (float*)&pbuf[0][0][0][0];   // 8 * 32 * 68 floats = 69632 B <= 90112
    #pragma unroll
    for (int mt = 0; mt < 2; ++mt)
        #pragma unroll
        for (int nd = 0; nd < 4; ++nd)
            #pragma unroll
            for (int j = 0; j < 4; ++j)
                pout[w * 2176 + (mt * 16 + lgrp * 4 + j) * 68 + nd * 16 + lrow] = o[mt][nd][j];
    __syncthreads();
    {
        const int r  = tid >> 4;           // 0..31
        const int c4 = tid & 15;           // 0..15
        f32x4 a4 = (f32x4){0.f, 0.f, 0.f, 0.f};
        #pragma unroll
        for (int ww = 0; ww < 8; ++ww) {
            const float* p = pout + ww * 2176 + r * 68 + c4 * 4;
            a4.x += p[0]; a4.y += p[1]; a4.z += p[2]; a4.w += p[3];
        }
        f32x4* og = (f32x4*)(out + base + (size_t)(t0 + r) * 64 + c4 * 4);
        __builtin_nontemporal_store(a4, og);
    }
}

extern "C" void kernel_launch(void* const* d_in, const int* in_sizes, int n_in,
                              void* d_out, int out_size, void* d_ws, size_t ws_size,
                              hipStream_t stream) {
    const float* q = (const float*)d_in[0];
    const float* k = (const float*)d_in[1];
    const float* v = (const float*)d_in[2];
    float* out  = (float*)d_out;
    float* attn = out + (size_t)OUT_ELEMS;

    // d_ws layout
    float* ctab = (float*)d_ws;                                  // T*32 f32
    float* stab = ctab + T_SEQ * 32;                             // T*32 f32
    unsigned short* wsu = (unsigned short*)(stab + T_SEQ * 32);
    const size_t NE = (size_t)BH_N * T_SEQ * D_HEAD;             // 4,194,304
    unsigned short* Qh  = wsu + 0 * NE;
    unsigned short* Ql  = wsu + 1 * NE;
    unsigned short* Kh  = wsu + 2 * NE;
    unsigned short* Kl  = wsu + 3 * NE;
    unsigned short* Vth = wsu + 4 * NE;
    unsigned short* Vtl = wsu + 5 * NE;                          // total ws ~48.5 MB

    rope_table_kernel<<<dim3((T_SEQ * 32 + 255) / 256), dim3(256), 0, stream>>>(ctab, stab);
    ropesplit_kernel<<<dim3(BH_N * T_SEQ / 16), dim3(256), 0, stream>>>(q, ctab, stab, Qh, Ql, 0.125f);
    ropesplit_kernel<<<dim3(BH_N * T_SEQ / 16), dim3(256), 0, stream>>>(k, ctab, stab, Kh, Kl, 1.0f);
    vtrans_kernel<<<dim3(T_SEQ / 64, BH_N), dim3(256), 0, stream>>>(v, Vth, Vtl);
    attn_mfma_kernel<<<dim3(T_SEQ / BM * BH_N), dim3(512), 0, stream>>>(Qh, Ql, Kh, Kl, Vth, Vtl, out, attn);
}